// Round 7
// baseline (646.217 us; speedup 1.0000x reference)
//
#include <hip/hip_runtime.h>

#define NTRAIN 65536
#define NQ     2048
#define KD     512
#define KNN    5

// ---------------- filter GEMM config ----------------
#define BM 128                   // train rows per chunk
#define BN 128                   // queries per block
#define BK 32                    // K step
#define CPB 4                    // chunks per block
#define GROUP (BM * CPB)         // 512 train rows per block
#define NCG (NTRAIN / GROUP)     // 128 chunk-groups
#define NQT (NQ / BN)            // 16 query tiles
#define NSTEP ((KD / BK) * CPB)  // 64 steps per block
#define MARGIN 2.0f
#define CAP 128

#define T2OFF 40960              // t2 LDS offset (after 40KB staging/merge area)
#define SMEMSZ (T2OFF + GROUP * 4)  // 43008

typedef short short8 __attribute__((ext_vector_type(8)));
typedef float f32x4 __attribute__((ext_vector_type(4)));

__device__ inline unsigned short f2bf(float f) {
    unsigned u = __float_as_uint(f);
    unsigned r = u + 0x7fffu + ((u >> 16) & 1u);
    return (unsigned short)(r >> 16);
}

template<int KK>
__device__ inline void ins5(float (&bd)[KK], int (&bi)[KK], float nd, int ni) {
    if (nd < bd[KK-1] || (nd == bd[KK-1] && ni < bi[KK-1])) {
#pragma unroll
        for (int k = 0; k < KK; ++k) {
            bool sw = (nd < bd[k]) || (nd == bd[k] && ni < bi[k]);
            float od = bd[k]; int oi = bi[k];
            bd[k] = sw ? nd : od; bi[k] = sw ? ni : oi;
            nd = sw ? od : nd;    ni = sw ? oi : ni;
        }
    }
}

__device__ inline void ins5v(float (&b5)[KNN], float v) {
    if (v < b5[KNN-1]) {
#pragma unroll
        for (int k = 0; k < KNN; ++k) {
            bool sw = v < b5[k];
            float o = b5[k];
            b5[k] = sw ? v : o;
            v = sw ? o : v;
        }
    }
}

// async global->LDS, 16B per lane; LDS dest = wave-uniform base + lane*16
__device__ inline void gload16(const void* g, void* l) {
    __builtin_amdgcn_global_load_lds(
        (const __attribute__((address_space(1))) void*)g,
        (__attribute__((address_space(3))) void*)l,
        16, 0, 0);
}

// ---------------- t2 (round-1 arithmetic) fused with xt bf16 conversion ----------------
__global__ __launch_bounds__(256)
void conv_xt_t2_kernel(const float* __restrict__ xt, unsigned short* __restrict__ xtb,
                       float* __restrict__ t2) {
    int row  = blockIdx.x * 4 + (threadIdx.x >> 6);
    int lane = threadIdx.x & 63;
    const float4* p = (const float4*)(xt + (size_t)row * KD);
    float s = 0.f;
#pragma unroll
    for (int c = 0; c < 2; ++c) {
        float4 v = p[lane + c * 64];
        s += v.x * v.x + v.y * v.y + v.z * v.z + v.w * v.w;
        unsigned short us[4] = { f2bf(v.x), f2bf(v.y), f2bf(v.z), f2bf(v.w) };
        *(unsigned long long*)(xtb + (size_t)row * KD + (size_t)(lane + c * 64) * 4) =
            *(const unsigned long long*)us;
    }
#pragma unroll
    for (int off = 32; off; off >>= 1) s += __shfl_down(s, off);
    if (lane == 0) t2[row] = s;
}

__global__ __launch_bounds__(256)
void conv_x_kernel(const float* __restrict__ in, unsigned short* __restrict__ out) {
    int i = blockIdx.x * 256 + threadIdx.x;           // 8 elems per thread
    const float4* p = (const float4*)in + (size_t)i * 2;
    float4 v0 = p[0], v1 = p[1];
    unsigned short us[8] = { f2bf(v0.x), f2bf(v0.y), f2bf(v0.z), f2bf(v0.w),
                             f2bf(v1.x), f2bf(v1.y), f2bf(v1.z), f2bf(v1.w) };
    *(uint4*)(out + (size_t)i * 8) = *(const uint4*)us;
}

// ---------------- filter: m97-contour MFMA GEMM (single buf, 2 barriers), 4 chunks/block ----
// LDS unit layout (verified): frag f, lane l -> row=f*16+(l&15), k=(l>>4)*8.., off f*1024+l*16
__global__ __launch_bounds__(256)
void knn_filter(const unsigned short* __restrict__ xb, const unsigned short* __restrict__ xtb,
                const float* __restrict__ t2g,
                float* __restrict__ candD, int* __restrict__ candI) {
    __shared__ __align__(16) char smem[SMEMSZ];

    const int tid  = threadIdx.x;
    const int w    = tid >> 6, lane = tid & 63;
    const int wm   = w & 1,  wn = w >> 1;

    // bijective XCD swizzle: 16 query-tiles of one chunk-group share an XCD
    const int b   = blockIdx.x;
    const int xcd = b & 7;
    const int r   = b >> 3;
    const int qt  = r & 15;
    const int cg  = xcd + 8 * (r >> 4);

    const int q0   = qt * BN;
    const int row0 = cg * GROUP;

    const int lrow = lane & 15;
    const int lk   = (lane >> 4) * 8;

    const unsigned short* Ab = xtb + (size_t)row0 * KD;
    const unsigned short* Bb = xb  + (size_t)q0  * KD;

    const int f0 = 2 * w, f1 = 2 * w + 1;
    const size_t offL0 = (size_t)(f0 * 16 + lrow) * KD + lk;   // per-lane element offset
    const size_t offL1 = (size_t)(f1 * 16 + lrow) * KD + lk;
    float* t2s = (float*)(smem + T2OFF);

    // FIXED staging buffers -> static LDS addresses with immediate offsets
    char* const bufA = smem;
    char* const bufB = smem + 8192;

    f32x4 acc[4][4];
#pragma unroll
    for (int m = 0; m < 4; ++m)
#pragma unroll
        for (int n = 0; n < 4; ++n) acc[m][n] = 0.f;

    float bd[4][KNN]; int bi[4][KNN];
#pragma unroll
    for (int n = 0; n < 4; ++n)
#pragma unroll
        for (int k = 0; k < KNN; ++k) { bd[n][k] = 3.4e38f; bi[n][k] = 0x7fffffff; }

    // t2 -> LDS (first epilogue read happens after >=2 barriers)
    t2s[tid]       = t2g[row0 + tid];
    t2s[256 + tid] = t2g[row0 + 256 + tid];

    for (int s = 0; s < NSTEP; ++s) {
        const unsigned short* Asrc = Ab + (size_t)(s >> 4) * (BM * KD) + (s & 15) * BK;
        const unsigned short* Bsrc = Bb + (s & 15) * BK;

        __syncthreads();   // all waves done reading buf from previous step
        gload16(Asrc + offL0, bufA + f0 * 1024);
        gload16(Asrc + offL1, bufA + f1 * 1024);
        gload16(Bsrc + offL0, bufB + f0 * 1024);
        gload16(Bsrc + offL1, bufB + f1 * 1024);
        __syncthreads();   // compiler emits vmcnt(0) drain -> buf ready for all waves

        short8 a[4], bfr[4];
#pragma unroll
        for (int m = 0; m < 4; ++m)
            a[m] = *(const short8*)(bufA + ((wm * 4 + m) * 64 + lane) * 16);
#pragma unroll
        for (int n = 0; n < 4; ++n)
            bfr[n] = *(const short8*)(bufB + ((wn * 4 + n) * 64 + lane) * 16);
#pragma unroll
        for (int m = 0; m < 4; ++m)
#pragma unroll
            for (int n = 0; n < 4; ++n)
                acc[m][n] = __builtin_amdgcn_mfma_f32_16x16x32_bf16(a[m], bfr[n], acc[m][n], 0, 0, 0);

        // per-chunk epilogue: fold into persistent top-5 (t2 from LDS)
        if ((s & 15) == 15) {
            const int ch  = s >> 4;
            const int rbl = wm * 64 + ((lane >> 4) << 2);      // local row in chunk
            const int c0  = row0 + ch * BM;
            float4 t2v[4];
#pragma unroll
            for (int m = 0; m < 4; ++m)
                t2v[m] = *(const float4*)(t2s + ch * BM + rbl + m * 16);
#pragma unroll
            for (int n = 0; n < 4; ++n)
#pragma unroll
                for (int m = 0; m < 4; ++m)
#pragma unroll
                    for (int r2 = 0; r2 < 4; ++r2) {
                        float sc = fmaf(-2.f, acc[m][n][r2], (&t2v[m].x)[r2]);
                        ins5(bd[n], bi[n], sc, c0 + rbl + m * 16 + r2);
                    }
#pragma unroll
            for (int m = 0; m < 4; ++m)
#pragma unroll
                for (int n = 0; n < 4; ++n) acc[m][n] = 0.f;
        }
    }

    __syncthreads();   // all waves done with staging LDS before merge reuses it

    // ---- block merge (once per block, covers all 4 chunks) ----
    float* MD = (float*)smem;                     // [128][40]
    int*   MI = (int*)(smem + 20480);
    const int slot = wm * 4 + (lane >> 4);        // 8 contributors per query
#pragma unroll
    for (int n = 0; n < 4; ++n) {
        int ql = wn * 64 + n * 16 + (lane & 15);
#pragma unroll
        for (int k = 0; k < KNN; ++k) {
            MD[ql * 40 + slot * KNN + k] = bd[n][k];
            MI[ql * 40 + slot * KNN + k] = bi[n][k];
        }
    }
    __syncthreads();
    if (tid < BN) {
        float fd[KNN]; int fi[KNN];
#pragma unroll
        for (int k = 0; k < KNN; ++k) { fd[k] = 3.4e38f; fi[k] = 0x7fffffff; }
        for (int j = 0; j < 40; ++j) ins5(fd, fi, MD[tid * 40 + j], MI[tid * 40 + j]);
        size_t base = ((size_t)(q0 + tid) * NCG + cg) * KNN;
#pragma unroll
        for (int k = 0; k < KNN; ++k) { candD[base + k] = fd[k]; candI[base + k] = fi[k]; }
    }
}

// ---------------- refine: global approx top-5 -> tight T -> exact rerank -> vote ----------
__global__ __launch_bounds__(256)
void knn_refine(const float* __restrict__ x, const float* __restrict__ xt,
                const float* __restrict__ t2,
                const float* __restrict__ candD, const int* __restrict__ candI,
                const int* __restrict__ y, int* __restrict__ out) {
    __shared__ float sv[256 * KNN];
    __shared__ float sv2[64 * KNN];
    __shared__ float xl[KD];
    __shared__ int   lidx[CAP];
    __shared__ float lex[CAP];
    __shared__ int   lcount;
    __shared__ float sT;

    const int q = blockIdx.x, tid = threadIdx.x;
    const float* cd = candD + (size_t)q * NCG * KNN;
    const int*   ci = candI + (size_t)q * NCG * KNN;

    for (int i = tid; i < KD; i += 256) xl[i] = x[(size_t)q * KD + i];

    // stage 1: per-thread top-5 (values only)
    float b5[KNN];
#pragma unroll
    for (int k = 0; k < KNN; ++k) b5[k] = 3.4e38f;
    for (int j = tid; j < NCG * KNN; j += 256) ins5v(b5, cd[j]);
#pragma unroll
    for (int k = 0; k < KNN; ++k) sv[tid * KNN + k] = b5[k];
    __syncthreads();

    // stage 2: 64 threads merge 4 lists each
    if (tid < 64) {
#pragma unroll
        for (int k = 0; k < KNN; ++k) b5[k] = 3.4e38f;
        for (int t = 0; t < 4; ++t)
#pragma unroll
            for (int k = 0; k < KNN; ++k) ins5v(b5, sv[(tid * 4 + t) * KNN + k]);
#pragma unroll
        for (int k = 0; k < KNN; ++k) sv2[tid * KNN + k] = b5[k];
    }
    __syncthreads();

    // stage 3: exact global approx 5th -> threshold
    if (tid == 0) {
#pragma unroll
        for (int k = 0; k < KNN; ++k) b5[k] = 3.4e38f;
        for (int j = 0; j < 64 * KNN; ++j) ins5v(b5, sv2[j]);
        sT = b5[KNN - 1] + MARGIN;
        lcount = 0;
    }
    __syncthreads();
    float T = sT;

    for (int j = tid; j < NCG * KNN; j += 256) {
        if (cd[j] <= T) {
            int p = atomicAdd(&lcount, 1);
            if (p < CAP) lidx[p] = ci[j];
        }
    }
    __syncthreads();
    int Q = min(lcount, CAP);

    // exact rerank: one thread per candidate, sequential fmaf over k (round-1 order)
    for (int j = tid; j < Q; j += 256) {
        int c = lidx[j];
        const float* tr = xt + (size_t)c * KD;
        float s = 0.f;
        for (int k = 0; k < KD; ++k) s = fmaf(xl[k], tr[k], s);
        lex[j] = fmaf(-2.f, s, t2[c]);
    }
    __syncthreads();

    if (tid == 0) {
        bool is64 = true;
#pragma unroll
        for (int i = 1; i < 64; i += 2) is64 = is64 && (y[i] == 0);
        float fd[KNN]; int fi[KNN];
#pragma unroll
        for (int k = 0; k < KNN; ++k) { fd[k] = 3.4e38f; fi[k] = 0x7fffffff; }
        for (int j = 0; j < Q; ++j) ins5(fd, fi, lex[j], lidx[j]);
        int lab[KNN];
#pragma unroll
        for (int k = 0; k < KNN; ++k) lab[k] = is64 ? y[2 * fi[k]] : y[fi[k]];
        int bestLab = 0x7fffffff, bestC = 0;
#pragma unroll
        for (int i = 0; i < KNN; ++i) {
            int c = 0;
#pragma unroll
            for (int j = 0; j < KNN; ++j) c += (lab[j] == lab[i]);
            if (c > bestC || (c == bestC && lab[i] < bestLab)) { bestC = c; bestLab = lab[i]; }
        }
        out[q] = bestLab;
    }
}

// =================== round-1 fp32 fallback (small ws) ===================
#define FB_QT 64
#define FB_TT 64
#define FB_KT 32
#define FB_NCHUNK 32
#define FB_CHUNK (NTRAIN / FB_NCHUNK)

__global__ __launch_bounds__(256)
void t2_kernel(const float* __restrict__ xt, float* __restrict__ t2) {
    int row  = blockIdx.x * 4 + (threadIdx.x >> 6);
    int lane = threadIdx.x & 63;
    const float4* p = (const float4*)(xt + (size_t)row * KD);
    float s = 0.f;
#pragma unroll
    for (int c = 0; c < 2; ++c) {
        float4 v = p[lane + c * 64];
        s += v.x * v.x + v.y * v.y + v.z * v.z + v.w * v.w;
    }
#pragma unroll
    for (int off = 32; off; off >>= 1) s += __shfl_down(s, off);
    if (lane == 0) t2[row] = s;
}

__global__ __launch_bounds__(256)
void fb_knn_partial(const float* __restrict__ x, const float* __restrict__ xt,
                    const float* __restrict__ t2,
                    float* __restrict__ candD, int* __restrict__ candI) {
    __shared__ __align__(16) float smem[FB_QT * 81 * 2];
    float (*Xs)[FB_QT + 4] = (float (*)[FB_QT + 4])smem;
    float (*Ts)[FB_TT + 4] = (float (*)[FB_TT + 4])(smem + FB_KT * (FB_QT + 4));
    float (*MD)[81]     = (float (*)[81])smem;
    int   (*MI)[81]     = (int   (*)[81])(smem + FB_QT * 81);

    const int tid = threadIdx.x;
    const int tx = tid & 15, ty = tid >> 4;
    const int q0 = blockIdx.x * FB_QT;
    const int c0 = blockIdx.y * FB_CHUNK;
    const int sq = tid >> 2, sc = tid & 3;

    float bd[4][KNN]; int bi_[4][KNN];
#pragma unroll
    for (int i = 0; i < 4; ++i)
#pragma unroll
        for (int k = 0; k < KNN; ++k) { bd[i][k] = 3.4e38f; bi_[i][k] = 0x7fffffff; }

    const float* xrow = x + (size_t)(q0 + sq) * KD;

    for (int s = 0; s < FB_CHUNK; s += FB_TT) {
        float acc[4][4];
#pragma unroll
        for (int i = 0; i < 4; ++i)
#pragma unroll
            for (int j = 0; j < 4; ++j) acc[i][j] = 0.f;
        const float* trow = xt + (size_t)(c0 + s + sq) * KD;
        for (int kt = 0; kt < KD; kt += FB_KT) {
            float4 xv0 = *(const float4*)(xrow + kt + sc * 8);
            float4 xv1 = *(const float4*)(xrow + kt + sc * 8 + 4);
            float4 tv0 = *(const float4*)(trow + kt + sc * 8);
            float4 tv1 = *(const float4*)(trow + kt + sc * 8 + 4);
            __syncthreads();
            Xs[sc*8+0][sq] = xv0.x; Xs[sc*8+1][sq] = xv0.y;
            Xs[sc*8+2][sq] = xv0.z; Xs[sc*8+3][sq] = xv0.w;
            Xs[sc*8+4][sq] = xv1.x; Xs[sc*8+5][sq] = xv1.y;
            Xs[sc*8+6][sq] = xv1.z; Xs[sc*8+7][sq] = xv1.w;
            Ts[sc*8+0][sq] = tv0.x; Ts[sc*8+1][sq] = tv0.y;
            Ts[sc*8+2][sq] = tv0.z; Ts[sc*8+3][sq] = tv0.w;
            Ts[sc*8+4][sq] = tv1.x; Ts[sc*8+5][sq] = tv1.y;
            Ts[sc*8+6][sq] = tv1.z; Ts[sc*8+7][sq] = tv1.w;
            __syncthreads();
#pragma unroll
            for (int k = 0; k < FB_KT; ++k) {
                const float4 av = *(const float4*)&Xs[k][ty * 4];
                const float4 bv = *(const float4*)&Ts[k][tx * 4];
                float a[4] = {av.x, av.y, av.z, av.w};
                float b[4] = {bv.x, bv.y, bv.z, bv.w};
#pragma unroll
                for (int i = 0; i < 4; ++i)
#pragma unroll
                    for (int j = 0; j < 4; ++j)
                        acc[i][j] = fmaf(a[i], b[j], acc[i][j]);
            }
        }
#pragma unroll
        for (int j = 0; j < 4; ++j) {
            int tcol = c0 + s + tx * 4 + j;
            float tt = t2[tcol];
#pragma unroll
            for (int i = 0; i < 4; ++i)
                ins5(bd[i], bi_[i], fmaf(-2.0f, acc[i][j], tt), tcol);
        }
    }
    __syncthreads();
#pragma unroll
    for (int i = 0; i < 4; ++i)
#pragma unroll
        for (int k = 0; k < KNN; ++k) {
            MD[ty * 4 + i][tx * KNN + k] = bd[i][k];
            MI[ty * 4 + i][tx * KNN + k] = bi_[i][k];
        }
    __syncthreads();
    if (tid < FB_QT) {
        int q = q0 + tid;
        for (int k = 0; k < KNN; ++k) {
            float best = 3.4e38f; int bidx = 0x7fffffff; int bj = -1;
            for (int j = 0; j < 16 * KNN; ++j) {
                float dv = MD[tid][j]; int iv = MI[tid][j];
                if (dv < best || (dv == best && iv < bidx)) { best = dv; bidx = iv; bj = j; }
            }
            MD[tid][bj] = 3.4e38f;
            candD[((size_t)q * FB_NCHUNK + blockIdx.y) * KNN + k] = best;
            candI[((size_t)q * FB_NCHUNK + blockIdx.y) * KNN + k] = bidx;
        }
    }
}

__global__ __launch_bounds__(256)
void fb_knn_final(const float* __restrict__ candD, const int* __restrict__ candI,
                  const int* __restrict__ y, int* __restrict__ out) {
    int q = blockIdx.x * 256 + threadIdx.x;
    if (q >= NQ) return;
    bool is64 = true;
#pragma unroll
    for (int i = 1; i < 64; i += 2) is64 = is64 && (y[i] == 0);
    float bd[KNN]; int bi_[KNN];
#pragma unroll
    for (int k = 0; k < KNN; ++k) { bd[k] = 3.4e38f; bi_[k] = 0x7fffffff; }
    for (int c = 0; c < FB_NCHUNK * KNN; ++c)
        ins5(bd, bi_, candD[(size_t)q * FB_NCHUNK * KNN + c], candI[(size_t)q * FB_NCHUNK * KNN + c]);
    int lab[KNN];
#pragma unroll
    for (int k = 0; k < KNN; ++k) lab[k] = is64 ? y[2 * bi_[k]] : y[bi_[k]];
    int bestLab = 0x7fffffff, bestC = 0;
#pragma unroll
    for (int i = 0; i < KNN; ++i) {
        int c = 0;
#pragma unroll
        for (int j = 0; j < KNN; ++j) c += (lab[j] == lab[i]);
        if (c > bestC || (c == bestC && lab[i] < bestLab)) { bestC = c; bestLab = lab[i]; }
    }
    out[q] = bestLab;
}

// =================== launch ===================
extern "C" void kernel_launch(void* const* d_in, const int* in_sizes, int n_in,
                              void* d_out, int out_size, void* d_ws, size_t ws_size,
                              hipStream_t stream) {
    const float* x  = (const float*)d_in[0];
    const float* xt = (const float*)d_in[1];
    const int*   y  = (const int*)d_in[2];
    int* out = (int*)d_out;

    // layout: xt_bf 64MB | x_bf 2MB | t2 256KB | candD 5.25MB | candI 5.25MB
    const size_t REQ = 79953920ull;
    if (ws_size >= REQ) {
        char* ws = (char*)d_ws;
        unsigned short* xt_bf = (unsigned short*)ws;
        unsigned short* x_bf  = (unsigned short*)(ws + 67108864);
        float*          t2    = (float*)(ws + 69206016);
        float*          candD = (float*)(ws + 69468160);
        int*            candI = (int*)(ws + 74711040);

        hipLaunchKernelGGL(conv_xt_t2_kernel, dim3(NTRAIN / 4), dim3(256), 0, stream, xt, xt_bf, t2);
        hipLaunchKernelGGL(conv_x_kernel, dim3(NQ * KD / 8 / 256), dim3(256), 0, stream, x, x_bf);
        hipLaunchKernelGGL(knn_filter, dim3(NQT * NCG), dim3(256), 0, stream,
                           x_bf, xt_bf, t2, candD, candI);
        hipLaunchKernelGGL(knn_refine, dim3(NQ), dim3(256), 0, stream,
                           x, xt, t2, candD, candI, y, out);
    } else {
        float* ws    = (float*)d_ws;
        float* t2    = ws;
        float* candD = ws + NTRAIN;
        int*   candI = (int*)(ws + NTRAIN + (size_t)NQ * FB_NCHUNK * KNN);
        hipLaunchKernelGGL(t2_kernel, dim3(NTRAIN / 4), dim3(256), 0, stream, xt, t2);
        hipLaunchKernelGGL(fb_knn_partial, dim3(NQ / FB_QT, FB_NCHUNK), dim3(256), 0, stream,
                           x, xt, t2, candD, candI);
        hipLaunchKernelGGL(fb_knn_final, dim3(NQ / 256), dim3(256), 0, stream,
                           candD, candI, y, out);
    }
}

// Round 8
// 572.068 us; speedup vs baseline: 1.1296x; 1.1296x over previous
//
#include <hip/hip_runtime.h>

#define NTRAIN 65536
#define NQ     2048
#define KD     512
#define KNN    5

// ---------------- filter GEMM config: 256x256 tile, 8 waves ----------------
#define BK 32
#define QT2 256                  // queries per block
#define TPB 2048                 // train rows per block
#define CH 256                   // chunk size (granularity of t2-fold)
#define NGRP (NTRAIN / TPB)      // 32 train groups
#define NQT2 (NQ / QT2)          // 8 query tiles
#define NSTEP2 ((KD / BK) * (TPB / CH))   // 128 steps
#define NSLOT (NGRP * KNN)       // 160 cand entries per query
#define MARGIN 2.0f
#define CAP 128

typedef short short8 __attribute__((ext_vector_type(8)));
typedef float f32x4 __attribute__((ext_vector_type(4)));

__device__ inline unsigned short f2bf(float f) {
    unsigned u = __float_as_uint(f);
    unsigned r = u + 0x7fffu + ((u >> 16) & 1u);
    return (unsigned short)(r >> 16);
}

template<int KK>
__device__ inline void ins5(float (&bd)[KK], int (&bi)[KK], float nd, int ni) {
    if (nd < bd[KK-1] || (nd == bd[KK-1] && ni < bi[KK-1])) {
#pragma unroll
        for (int k = 0; k < KK; ++k) {
            bool sw = (nd < bd[k]) || (nd == bd[k] && ni < bi[k]);
            float od = bd[k]; int oi = bi[k];
            bd[k] = sw ? nd : od; bi[k] = sw ? ni : oi;
            nd = sw ? od : nd;    ni = sw ? oi : ni;
        }
    }
}

__device__ inline void ins5v(float (&b5)[KNN], float v) {
    if (v < b5[KNN-1]) {
#pragma unroll
        for (int k = 0; k < KNN; ++k) {
            bool sw = v < b5[k];
            float o = b5[k];
            b5[k] = sw ? v : o;
            v = sw ? o : v;
        }
    }
}

// async global->LDS, 16B per lane; LDS dest = wave-uniform base + lane*16
__device__ inline void gload16(const void* g, void* l) {
    __builtin_amdgcn_global_load_lds(
        (const __attribute__((address_space(1))) void*)g,
        (__attribute__((address_space(3))) void*)l,
        16, 0, 0);
}

// ---------------- t2 (round-1 arithmetic) fused with xt bf16 conversion ----------------
__global__ __launch_bounds__(256)
void conv_xt_t2_kernel(const float* __restrict__ xt, unsigned short* __restrict__ xtb,
                       float* __restrict__ t2) {
    int row  = blockIdx.x * 4 + (threadIdx.x >> 6);
    int lane = threadIdx.x & 63;
    const float4* p = (const float4*)(xt + (size_t)row * KD);
    float s = 0.f;
#pragma unroll
    for (int c = 0; c < 2; ++c) {
        float4 v = p[lane + c * 64];
        s += v.x * v.x + v.y * v.y + v.z * v.z + v.w * v.w;
        unsigned short us[4] = { f2bf(v.x), f2bf(v.y), f2bf(v.z), f2bf(v.w) };
        *(unsigned long long*)(xtb + (size_t)row * KD + (size_t)(lane + c * 64) * 4) =
            *(const unsigned long long*)us;
    }
#pragma unroll
    for (int off = 32; off; off >>= 1) s += __shfl_down(s, off);
    if (lane == 0) t2[row] = s;
}

__global__ __launch_bounds__(256)
void conv_x_kernel(const float* __restrict__ in, unsigned short* __restrict__ out) {
    int i = blockIdx.x * 256 + threadIdx.x;           // 8 elems per thread
    const float4* p = (const float4*)in + (size_t)i * 2;
    float4 v0 = p[0], v1 = p[1];
    unsigned short us[8] = { f2bf(v0.x), f2bf(v0.y), f2bf(v0.z), f2bf(v0.w),
                             f2bf(v1.x), f2bf(v1.y), f2bf(v1.z), f2bf(v1.w) };
    *(uint4*)(out + (size_t)i * 8) = *(const uint4*)us;
}

// ---------------- filter: 256x256-tile MFMA GEMM, 8 chunks/block, fused top-5 ----------
// LDS unit layout (verified): frag f, lane l -> row=f*16+(l&15), k=(l>>4)*8.., off f*1024+l*16
__global__ __launch_bounds__(512, 2)
void knn_filter(const unsigned short* __restrict__ xb, const unsigned short* __restrict__ xtb,
                const float* __restrict__ t2g,
                float* __restrict__ candD, int* __restrict__ candI) {
    __shared__ __align__(16) char smem[81920];   // staging 32KB | merge 80KB (aliased)

    const int tid  = threadIdx.x;
    const int w    = tid >> 6, lane = tid & 63;
    const int wm   = w & 1,  wn = w >> 1;         // wm 0..1 (train half), wn 0..3 (query quarter)
    const int lrow = lane & 15, lhi = lane >> 4;  // lhi 0..3

    const int qt   = blockIdx.x >> 5;             // 0..7
    const int grp  = blockIdx.x & 31;             // 0..31 (same grp -> same XCD since 32%8==0)
    const int q0   = qt * QT2;
    const int row0 = grp * TPB;

    const unsigned short* Ab = xtb + (size_t)row0 * KD;
    const unsigned short* Bb = xb  + (size_t)q0  * KD;

    char* const bufA = smem;                      // 16KB (16 units)
    char* const bufB = smem + 16384;              // 16KB (16 units)

    f32x4 acc[8][4];
#pragma unroll
    for (int m = 0; m < 8; ++m)
#pragma unroll
        for (int n = 0; n < 4; ++n) acc[m][n] = 0.f;

    float bd[4][KNN]; int bi[4][KNN];
#pragma unroll
    for (int n = 0; n < 4; ++n)
#pragma unroll
        for (int k = 0; k < KNN; ++k) { bd[n][k] = 3.4e38f; bi[n][k] = 0x7fffffff; }

    for (int s = 0; s < NSTEP2; ++s) {
        const int ch = s >> 4;
        const int kt = (s & 15) * BK;

        __syncthreads();   // all waves done reading buf from previous step
        if (w < 4) {       // waves 0-3 stage A (16 units)
            const unsigned short* Asrc = Ab + (size_t)ch * (CH * KD) + kt;
#pragma unroll
            for (int i = 0; i < 4; ++i) {
                const int f = w * 4 + i;
                gload16(Asrc + (size_t)(f * 16 + lrow) * KD + lhi * 8, bufA + f * 1024);
            }
        } else {           // waves 4-7 stage B (16 units)
            const unsigned short* Bsrc = Bb + kt;
#pragma unroll
            for (int i = 0; i < 4; ++i) {
                const int f = (w - 4) * 4 + i;
                gload16(Bsrc + (size_t)(f * 16 + lrow) * KD + lhi * 8, bufB + f * 1024);
            }
        }
        __syncthreads();   // vmcnt drain -> buf ready for all waves

        short8 a[8], bfr[4];
#pragma unroll
        for (int m = 0; m < 8; ++m)
            a[m] = *(const short8*)(bufA + ((wm * 8 + m) * 64 + lane) * 16);
#pragma unroll
        for (int n = 0; n < 4; ++n)
            bfr[n] = *(const short8*)(bufB + ((wn * 4 + n) * 64 + lane) * 16);
#pragma unroll
        for (int m = 0; m < 8; ++m)
#pragma unroll
            for (int n = 0; n < 4; ++n)
                acc[m][n] = __builtin_amdgcn_mfma_f32_16x16x32_bf16(a[m], bfr[n], acc[m][n], 0, 0, 0);

        // per-chunk epilogue: fold scores into persistent per-thread top-5, reset acc
        if ((s & 15) == 15) {
            const int c0  = row0 + ch * CH;
            const int rbl = wm * 128 + lhi * 4;        // + m*16 + r within chunk
#pragma unroll
            for (int m = 0; m < 8; ++m) {
                const float4 t2v = *(const float4*)(t2g + c0 + rbl + m * 16);
#pragma unroll
                for (int n = 0; n < 4; ++n)
#pragma unroll
                    for (int r2 = 0; r2 < 4; ++r2) {
                        float sc = fmaf(-2.f, acc[m][n][r2], (&t2v.x)[r2]);
                        ins5(bd[n], bi[n], sc, c0 + rbl + m * 16 + r2);
                    }
            }
#pragma unroll
            for (int m = 0; m < 8; ++m)
#pragma unroll
                for (int n = 0; n < 4; ++n) acc[m][n] = 0.f;
        }
    }

    __syncthreads();   // all waves done with staging LDS before merge reuses it

    // ---- single block merge: 8 slots x top-5 per query ----
    float* MD = (float*)smem;                     // [256][40] = 40KB
    int*   MI = (int*)(smem + 40960);             // [256][40] = 40KB
    const int slot = wm * 4 + lhi;                // 0..7
#pragma unroll
    for (int n = 0; n < 4; ++n) {
        const int ql = wn * 64 + n * 16 + lrow;   // 0..255
#pragma unroll
        for (int k = 0; k < KNN; ++k) {
            MD[ql * 40 + slot * KNN + k] = bd[n][k];
            MI[ql * 40 + slot * KNN + k] = bi[n][k];
        }
    }
    __syncthreads();
    if (tid < QT2) {
        float fd[KNN]; int fi[KNN];
#pragma unroll
        for (int k = 0; k < KNN; ++k) { fd[k] = 3.4e38f; fi[k] = 0x7fffffff; }
        for (int j = 0; j < 8 * KNN; ++j) ins5(fd, fi, MD[tid * 40 + j], MI[tid * 40 + j]);
        size_t base = ((size_t)(q0 + tid) * NGRP + grp) * KNN;
#pragma unroll
        for (int k = 0; k < KNN; ++k) { candD[base + k] = fd[k]; candI[base + k] = fi[k]; }
    }
}

// ---------------- refine: global approx top-5 -> tight T -> exact rerank -> vote ----------
__global__ __launch_bounds__(256)
void knn_refine(const float* __restrict__ x, const float* __restrict__ xt,
                const float* __restrict__ t2,
                const float* __restrict__ candD, const int* __restrict__ candI,
                const int* __restrict__ y, int* __restrict__ out) {
    __shared__ float sv[256 * KNN];
    __shared__ float sv2[64 * KNN];
    __shared__ float xl[KD];
    __shared__ int   lidx[CAP];
    __shared__ float lex[CAP];
    __shared__ int   lcount;
    __shared__ float sT;

    const int q = blockIdx.x, tid = threadIdx.x;
    const float* cd = candD + (size_t)q * NSLOT;
    const int*   ci = candI + (size_t)q * NSLOT;

    for (int i = tid; i < KD; i += 256) xl[i] = x[(size_t)q * KD + i];

    // stage 1: per-thread top-5 (values only)
    float b5[KNN];
#pragma unroll
    for (int k = 0; k < KNN; ++k) b5[k] = 3.4e38f;
    for (int j = tid; j < NSLOT; j += 256) ins5v(b5, cd[j]);
#pragma unroll
    for (int k = 0; k < KNN; ++k) sv[tid * KNN + k] = b5[k];
    __syncthreads();

    // stage 2: 64 threads merge 4 lists each
    if (tid < 64) {
#pragma unroll
        for (int k = 0; k < KNN; ++k) b5[k] = 3.4e38f;
        for (int t = 0; t < 4; ++t)
#pragma unroll
            for (int k = 0; k < KNN; ++k) ins5v(b5, sv[(tid * 4 + t) * KNN + k]);
#pragma unroll
        for (int k = 0; k < KNN; ++k) sv2[tid * KNN + k] = b5[k];
    }
    __syncthreads();

    // stage 3: exact global approx 5th -> threshold
    if (tid == 0) {
#pragma unroll
        for (int k = 0; k < KNN; ++k) b5[k] = 3.4e38f;
        for (int j = 0; j < 64 * KNN; ++j) ins5v(b5, sv2[j]);
        sT = b5[KNN - 1] + MARGIN;
        lcount = 0;
    }
    __syncthreads();
    float T = sT;

    for (int j = tid; j < NSLOT; j += 256) {
        if (cd[j] <= T) {
            int p = atomicAdd(&lcount, 1);
            if (p < CAP) lidx[p] = ci[j];
        }
    }
    __syncthreads();
    int Q = min(lcount, CAP);

    // exact rerank: one thread per candidate, sequential fmaf over k (round-1 order)
    for (int j = tid; j < Q; j += 256) {
        int c = lidx[j];
        const float* tr = xt + (size_t)c * KD;
        float s = 0.f;
        for (int k = 0; k < KD; ++k) s = fmaf(xl[k], tr[k], s);
        lex[j] = fmaf(-2.f, s, t2[c]);
    }
    __syncthreads();

    if (tid == 0) {
        bool is64 = true;
#pragma unroll
        for (int i = 1; i < 64; i += 2) is64 = is64 && (y[i] == 0);
        float fd[KNN]; int fi[KNN];
#pragma unroll
        for (int k = 0; k < KNN; ++k) { fd[k] = 3.4e38f; fi[k] = 0x7fffffff; }
        for (int j = 0; j < Q; ++j) ins5(fd, fi, lex[j], lidx[j]);
        int lab[KNN];
#pragma unroll
        for (int k = 0; k < KNN; ++k) lab[k] = is64 ? y[2 * fi[k]] : y[fi[k]];
        int bestLab = 0x7fffffff, bestC = 0;
#pragma unroll
        for (int i = 0; i < KNN; ++i) {
            int c = 0;
#pragma unroll
            for (int j = 0; j < KNN; ++j) c += (lab[j] == lab[i]);
            if (c > bestC || (c == bestC && lab[i] < bestLab)) { bestC = c; bestLab = lab[i]; }
        }
        out[q] = bestLab;
    }
}

// =================== round-1 fp32 fallback (small ws) ===================
#define FB_QT 64
#define FB_TT 64
#define FB_KT 32
#define FB_NCHUNK 32
#define FB_CHUNK (NTRAIN / FB_NCHUNK)

__global__ __launch_bounds__(256)
void t2_kernel(const float* __restrict__ xt, float* __restrict__ t2) {
    int row  = blockIdx.x * 4 + (threadIdx.x >> 6);
    int lane = threadIdx.x & 63;
    const float4* p = (const float4*)(xt + (size_t)row * KD);
    float s = 0.f;
#pragma unroll
    for (int c = 0; c < 2; ++c) {
        float4 v = p[lane + c * 64];
        s += v.x * v.x + v.y * v.y + v.z * v.z + v.w * v.w;
    }
#pragma unroll
    for (int off = 32; off; off >>= 1) s += __shfl_down(s, off);
    if (lane == 0) t2[row] = s;
}

__global__ __launch_bounds__(256)
void fb_knn_partial(const float* __restrict__ x, const float* __restrict__ xt,
                    const float* __restrict__ t2,
                    float* __restrict__ candD, int* __restrict__ candI) {
    __shared__ __align__(16) float smem[FB_QT * 81 * 2];
    float (*Xs)[FB_QT + 4] = (float (*)[FB_QT + 4])smem;
    float (*Ts)[FB_TT + 4] = (float (*)[FB_TT + 4])(smem + FB_KT * (FB_QT + 4));
    float (*MD)[81]     = (float (*)[81])smem;
    int   (*MI)[81]     = (int   (*)[81])(smem + FB_QT * 81);

    const int tid = threadIdx.x;
    const int tx = tid & 15, ty = tid >> 4;
    const int q0 = blockIdx.x * FB_QT;
    const int c0 = blockIdx.y * FB_CHUNK;
    const int sq = tid >> 2, sc = tid & 3;

    float bd[4][KNN]; int bi_[4][KNN];
#pragma unroll
    for (int i = 0; i < 4; ++i)
#pragma unroll
        for (int k = 0; k < KNN; ++k) { bd[i][k] = 3.4e38f; bi_[i][k] = 0x7fffffff; }

    const float* xrow = x + (size_t)(q0 + sq) * KD;

    for (int s = 0; s < FB_CHUNK; s += FB_TT) {
        float acc[4][4];
#pragma unroll
        for (int i = 0; i < 4; ++i)
#pragma unroll
            for (int j = 0; j < 4; ++j) acc[i][j] = 0.f;
        const float* trow = xt + (size_t)(c0 + s + sq) * KD;
        for (int kt = 0; kt < KD; kt += FB_KT) {
            float4 xv0 = *(const float4*)(xrow + kt + sc * 8);
            float4 xv1 = *(const float4*)(xrow + kt + sc * 8 + 4);
            float4 tv0 = *(const float4*)(trow + kt + sc * 8);
            float4 tv1 = *(const float4*)(trow + kt + sc * 8 + 4);
            __syncthreads();
            Xs[sc*8+0][sq] = xv0.x; Xs[sc*8+1][sq] = xv0.y;
            Xs[sc*8+2][sq] = xv0.z; Xs[sc*8+3][sq] = xv0.w;
            Xs[sc*8+4][sq] = xv1.x; Xs[sc*8+5][sq] = xv1.y;
            Xs[sc*8+6][sq] = xv1.z; Xs[sc*8+7][sq] = xv1.w;
            Ts[sc*8+0][sq] = tv0.x; Ts[sc*8+1][sq] = tv0.y;
            Ts[sc*8+2][sq] = tv0.z; Ts[sc*8+3][sq] = tv0.w;
            Ts[sc*8+4][sq] = tv1.x; Ts[sc*8+5][sq] = tv1.y;
            Ts[sc*8+6][sq] = tv1.z; Ts[sc*8+7][sq] = tv1.w;
            __syncthreads();
#pragma unroll
            for (int k = 0; k < FB_KT; ++k) {
                const float4 av = *(const float4*)&Xs[k][ty * 4];
                const float4 bv = *(const float4*)&Ts[k][tx * 4];
                float a[4] = {av.x, av.y, av.z, av.w};
                float b[4] = {bv.x, bv.y, bv.z, bv.w};
#pragma unroll
                for (int i = 0; i < 4; ++i)
#pragma unroll
                    for (int j = 0; j < 4; ++j)
                        acc[i][j] = fmaf(a[i], b[j], acc[i][j]);
            }
        }
#pragma unroll
        for (int j = 0; j < 4; ++j) {
            int tcol = c0 + s + tx * 4 + j;
            float tt = t2[tcol];
#pragma unroll
            for (int i = 0; i < 4; ++i)
                ins5(bd[i], bi_[i], fmaf(-2.0f, acc[i][j], tt), tcol);
        }
    }
    __syncthreads();
#pragma unroll
    for (int i = 0; i < 4; ++i)
#pragma unroll
        for (int k = 0; k < KNN; ++k) {
            MD[ty * 4 + i][tx * KNN + k] = bd[i][k];
            MI[ty * 4 + i][tx * KNN + k] = bi_[i][k];
        }
    __syncthreads();
    if (tid < FB_QT) {
        int q = q0 + tid;
        for (int k = 0; k < KNN; ++k) {
            float best = 3.4e38f; int bidx = 0x7fffffff; int bj = -1;
            for (int j = 0; j < 16 * KNN; ++j) {
                float dv = MD[tid][j]; int iv = MI[tid][j];
                if (dv < best || (dv == best && iv < bidx)) { best = dv; bidx = iv; bj = j; }
            }
            MD[tid][bj] = 3.4e38f;
            candD[((size_t)q * FB_NCHUNK + blockIdx.y) * KNN + k] = best;
            candI[((size_t)q * FB_NCHUNK + blockIdx.y) * KNN + k] = bidx;
        }
    }
}

__global__ __launch_bounds__(256)
void fb_knn_final(const float* __restrict__ candD, const int* __restrict__ candI,
                  const int* __restrict__ y, int* __restrict__ out) {
    int q = blockIdx.x * 256 + threadIdx.x;
    if (q >= NQ) return;
    bool is64 = true;
#pragma unroll
    for (int i = 1; i < 64; i += 2) is64 = is64 && (y[i] == 0);
    float bd[KNN]; int bi_[KNN];
#pragma unroll
    for (int k = 0; k < KNN; ++k) { bd[k] = 3.4e38f; bi_[k] = 0x7fffffff; }
    for (int c = 0; c < FB_NCHUNK * KNN; ++c)
        ins5(bd, bi_, candD[(size_t)q * FB_NCHUNK * KNN + c], candI[(size_t)q * FB_NCHUNK * KNN + c]);
    int lab[KNN];
#pragma unroll
    for (int k = 0; k < KNN; ++k) lab[k] = is64 ? y[2 * bi_[k]] : y[bi_[k]];
    int bestLab = 0x7fffffff, bestC = 0;
#pragma unroll
    for (int i = 0; i < KNN; ++i) {
        int c = 0;
#pragma unroll
        for (int j = 0; j < KNN; ++j) c += (lab[j] == lab[i]);
        if (c > bestC || (c == bestC && lab[i] < bestLab)) { bestC = c; bestLab = lab[i]; }
    }
    out[q] = bestLab;
}

// =================== launch ===================
extern "C" void kernel_launch(void* const* d_in, const int* in_sizes, int n_in,
                              void* d_out, int out_size, void* d_ws, size_t ws_size,
                              hipStream_t stream) {
    const float* x  = (const float*)d_in[0];
    const float* xt = (const float*)d_in[1];
    const int*   y  = (const int*)d_in[2];
    int* out = (int*)d_out;

    // layout: xt_bf 64MB | x_bf 2MB | t2 256KB | candD 1.31MB | candI 1.31MB
    const size_t REQ = 72089600ull;
    if (ws_size >= REQ) {
        char* ws = (char*)d_ws;
        unsigned short* xt_bf = (unsigned short*)ws;
        unsigned short* x_bf  = (unsigned short*)(ws + 67108864);
        float*          t2    = (float*)(ws + 69206016);
        float*          candD = (float*)(ws + 69468160);
        int*            candI = (int*)(ws + 70778880);

        hipLaunchKernelGGL(conv_xt_t2_kernel, dim3(NTRAIN / 4), dim3(256), 0, stream, xt, xt_bf, t2);
        hipLaunchKernelGGL(conv_x_kernel, dim3(NQ * KD / 8 / 256), dim3(256), 0, stream, x, x_bf);
        hipLaunchKernelGGL(knn_filter, dim3(NQT2 * NGRP), dim3(512), 0, stream,
                           x_bf, xt_bf, t2, candD, candI);
        hipLaunchKernelGGL(knn_refine, dim3(NQ), dim3(256), 0, stream,
                           x, xt, t2, candD, candI, y, out);
    } else {
        float* ws    = (float*)d_ws;
        float* t2    = ws;
        float* candD = ws + NTRAIN;
        int*   candI = (int*)(ws + NTRAIN + (size_t)NQ * FB_NCHUNK * KNN);
        hipLaunchKernelGGL(t2_kernel, dim3(NTRAIN / 4), dim3(256), 0, stream, xt, t2);
        hipLaunchKernelGGL(fb_knn_partial, dim3(NQ / FB_QT, FB_NCHUNK), dim3(256), 0, stream,
                           x, xt, t2, candD, candI);
        hipLaunchKernelGGL(fb_knn_final, dim3(NQ / 256), dim3(256), 0, stream,
                           candD, candI, y, out);
    }
}